// Round 8
// baseline (221.358 us; speedup 1.0000x reference)
//
#include <hip/hip_runtime.h>

typedef unsigned short u16;
typedef unsigned int u32;
typedef __bf16 bf16x8 __attribute__((ext_vector_type(8)));
typedef float f32x4 __attribute__((ext_vector_type(4)));
typedef short s16x4 __attribute__((ext_vector_type(4)));

#define AS1 __attribute__((address_space(1)))
#define AS3 __attribute__((address_space(3)))

__device__ __forceinline__ f32x4 mfma16(bf16x8 a, bf16x8 b, f32x4 c) {
    return __builtin_amdgcn_mfma_f32_16x16x32_bf16(a, b, c, 0, 0, 0);
}
// K=16 shape: B-operand layout == C/D layout (transpose-free PV)
__device__ __forceinline__ f32x4 mfma16k16(s16x4 a, s16x4 b, f32x4 c) {
    return __builtin_amdgcn_mfma_f32_16x16x16bf16_1k(a, b, c, 0, 0, 0);
}

__device__ __forceinline__ u16 f2bf(float f) {
    return __builtin_bit_cast(u16, (__bf16)f);
}

__device__ __forceinline__ void gld16(const u16* g, u16* l) {
    __builtin_amdgcn_global_load_lds((AS1 void*)g, (AS3 void*)l, 16, 0, 0);
}

// 8x fp32 -> 8x bf16 packed (compiler emits v_cvt_pk_bf16_f32 pairs)
__device__ __forceinline__ uint4 pack8(float4 a, float4 b) {
    return make_uint4((u32)f2bf(a.x) | ((u32)f2bf(a.y) << 16),
                      (u32)f2bf(a.z) | ((u32)f2bf(a.w) << 16),
                      (u32)f2bf(b.x) | ((u32)f2bf(b.y) << 16),
                      (u32)f2bf(b.z) | ((u32)f2bf(b.w) << 16));
}

// Raw barrier: drain LDS ops only; global prefetch loads stay in flight (T4).
__device__ __forceinline__ void barrier_nodrain() {
    asm volatile("s_waitcnt lgkmcnt(0)" ::: "memory");
    __builtin_amdgcn_s_barrier();
    asm volatile("" ::: "memory");
}

// ---------------- weights-only fp32 -> bf16 (activations convert in-GEMM) ----------
__global__ __launch_bounds__(256) void cvt_w(const float* __restrict__ wq, const float* __restrict__ wk,
                                             const float* __restrict__ wv, const float* __restrict__ wo,
                                             u16* __restrict__ wqo, u16* __restrict__ wko,
                                             u16* __restrict__ wvo, u16* __restrict__ woo) {
    const int y = blockIdx.y;
    const float* x; u16* o;
    switch (y) {
        case 0: x = wq; o = wqo; break;
        case 1: x = wk; o = wko; break;
        case 2: x = wv; o = wvo; break;
        default: x = wo; o = woo; break;
    }
    const int i = (blockIdx.x * 256 + threadIdx.x) * 4;  // grid 1024 covers 1<<20 exactly
    float4 vv = *(const float4*)(x + i);
    u32 lo = (u32)f2bf(vv.x) | ((u32)f2bf(vv.y) << 16);
    u32 hi = (u32)f2bf(vv.z) | ((u32)f2bf(vv.w) << 16);
    *(uint2*)(o + i) = make_uint2(lo, hi);
}

// ---------------- reg-staged GEMM (flash staging pattern): C = A @ Bt^T ----------------
// 128x128 tile, BK=64, 256 thr. fp32 operands convert during staging (pack8) --
// eliminates the activation cvt round-trip. Schedule per K-step (== flash_attn's):
//   stage(buf from regs) -> prefetch(next K-step into regs) -> barrier_nodrain
//   (lgkmcnt only; global loads stay in flight across the barrier, T4) -> MFMA.
// The compiler's vmcnt wait lands at next iter's ds_write -- after a full compute
// phase -> load latency hidden (round-5's failure had no dbuf: latency exposed).
// Buffer safety: stage(t) writes buf; last read of buf was compute(t-2), and every
// wave passed barrier(t-1) only after finishing compute(t-2). LDS stride 72 elems
// (flash's padding) -> ~2-way read conflicts, no XOR swizzle needed. LDS 72 KB.
template <bool AF32, bool BF32>
__device__ __forceinline__ void gemm_rs(const void* __restrict__ Apv, const void* __restrict__ Btv,
                                        u16* __restrict__ Cp, int K, int N, int m0, int n0,
                                        float oscale) {
    constexpr int LDT = 72;
    __shared__ __align__(16) u16 As[2][128 * LDT];
    __shared__ __align__(16) u16 Bs[2][128 * LDT];
    const int tid = threadIdx.x;
    const int lane = tid & 63, wave = tid >> 6;
    const int l16 = lane & 15, q4 = lane >> 4;
    const int wm = (wave >> 1) * 64, wn = (wave & 1) * 64;

    const f32x4 fz = {0.f, 0.f, 0.f, 0.f};
    f32x4 acc[4][4];
#pragma unroll
    for (int i = 0; i < 4; ++i)
#pragma unroll
        for (int j = 0; j < 4; ++j) acc[i][j] = fz;

    // staging: thread (sr, pos) covers rows sr+{0,32,64,96}, 16B chunk pos of each
    const int sr = tid >> 3, pos = (tid & 7) * 8;  // pos in elems
    const float* Af = (const float*)Apv + (size_t)(m0 + sr) * K + pos;
    const u16*   Ab = (const u16*)Apv + (size_t)(m0 + sr) * K + pos;
    const float* Bf = (const float*)Btv + (size_t)(n0 + sr) * K + pos;
    const u16*   Bb = (const u16*)Btv + (size_t)(n0 + sr) * K + pos;

    float4 pa[4][2], pb[4][2];
    uint4 qa[4], qb[4];
    auto prefetch = [&](int k0) {
#pragma unroll
        for (int p = 0; p < 4; ++p) {
            const size_t ro = (size_t)(p * 32) * K + k0;
            if constexpr (AF32) {
                pa[p][0] = *(const float4*)(Af + ro);
                pa[p][1] = *(const float4*)(Af + ro + 4);
            } else {
                qa[p] = *(const uint4*)(Ab + ro);
            }
            if constexpr (BF32) {
                pb[p][0] = *(const float4*)(Bf + ro);
                pb[p][1] = *(const float4*)(Bf + ro + 4);
            } else {
                qb[p] = *(const uint4*)(Bb + ro);
            }
        }
    };
    auto stage = [&](int buf) {
#pragma unroll
        for (int p = 0; p < 4; ++p) {
            uint4 wa, wb;
            if constexpr (AF32) wa = pack8(pa[p][0], pa[p][1]); else wa = qa[p];
            if constexpr (BF32) wb = pack8(pb[p][0], pb[p][1]); else wb = qb[p];
            *(uint4*)&As[buf][(sr + p * 32) * LDT + pos] = wa;
            *(uint4*)&Bs[buf][(sr + p * 32) * LDT + pos] = wb;
        }
    };

    prefetch(0);
    for (int k0 = 0; k0 < K; k0 += 64) {
        const int buf = (k0 >> 6) & 1;
        stage(buf);
        prefetch(k0 + 64 < K ? k0 + 64 : 0);  // wrap: harmless dead load
        barrier_nodrain();
#pragma unroll
        for (int h = 0; h < 2; ++h) {  // two K=32 halves of the 64-col tile
            bf16x8 af[4], bfr[4];
#pragma unroll
            for (int i = 0; i < 4; ++i)
                af[i] = *(const bf16x8*)&As[buf][(wm + i * 16 + l16) * LDT + (h * 4 + q4) * 8];
#pragma unroll
            for (int j = 0; j < 4; ++j)
                bfr[j] = *(const bf16x8*)&Bs[buf][(wn + j * 16 + l16) * LDT + (h * 4 + q4) * 8];
#pragma unroll
            for (int i = 0; i < 4; ++i)
#pragma unroll
                for (int j = 0; j < 4; ++j) acc[i][j] = mfma16(af[i], bfr[j], acc[i][j]);
        }
    }

#pragma unroll
    for (int i = 0; i < 4; ++i) {
        const int row = m0 + wm + i * 16 + q4 * 4;
#pragma unroll
        for (int j = 0; j < 4; ++j) {
            const int col = n0 + wn + j * 16 + l16;
#pragma unroll
            for (int r = 0; r < 4; ++r)
                Cp[(size_t)(row + r) * N + col] = f2bf(acc[i][j][r] * oscale);
        }
    }
}

// ---------------- gld16 GEMM (round-6 config, for bf16-only gemm_out) ----------------
template <int BM, int BN, bool BF16OUT>
__device__ __forceinline__ void gemm_core(const u16* __restrict__ A, const u16* __restrict__ Bt,
                                          void* __restrict__ Cp, int K, int N, int m0, int n0,
                                          float oscale) {
    constexpr int WROWS = BM / 64;
    constexpr int WCOLS = 4 / WROWS;
    constexpr int BFR = BN / WCOLS / 16;
    constexpr int RPWA = BM / 4;
    constexpr int RPWB = BN / 4;
    constexpr int PA = RPWA / 8, PB = RPWB / 8;
    __shared__ __align__(16) u16 As[BM * 64];
    __shared__ __align__(16) u16 Bs[BN * 64];
    const int tid = threadIdx.x;
    const int lane = tid & 63, wave = tid >> 6;
    const int l16 = lane & 15, q4 = lane >> 4;
    const int wm = (wave / WCOLS) * 64, wn = (wave % WCOLS) * (BFR * 16);

    const f32x4 fz = {0.f, 0.f, 0.f, 0.f};
    f32x4 acc[4][BFR];
#pragma unroll
    for (int i = 0; i < 4; ++i)
#pragma unroll
        for (int j = 0; j < BFR; ++j) acc[i][j] = fz;

    const int srow = lane >> 3;
    const int clog = (lane & 7) ^ srow;  // source pre-swizzle (gld16 dest is linear)
    const u16* Ag = A + (size_t)(m0 + wave * RPWA + srow) * K + clog * 8;
    const u16* Bg = Bt + (size_t)(n0 + wave * RPWB + srow) * K + clog * 8;
    const int rk = l16 & 7;

    for (int k0 = 0; k0 < K; k0 += 64) {
        __syncthreads();
#pragma unroll
        for (int p = 0; p < PA; ++p)
            gld16(Ag + (size_t)(p * 8) * K + k0, As + (wave * RPWA + p * 8) * 64);
#pragma unroll
        for (int p = 0; p < PB; ++p)
            gld16(Bg + (size_t)(p * 8) * K + k0, Bs + (wave * RPWB + p * 8) * 64);
        __syncthreads();
#pragma unroll
        for (int h = 0; h < 2; ++h) {
            const int cs = ((h * 4 + q4) ^ rk) * 8;
            bf16x8 af[4], bfr[BFR];
#pragma unroll
            for (int i = 0; i < 4; ++i)
                af[i] = *(const bf16x8*)&As[(wm + i * 16 + l16) * 64 + cs];
#pragma unroll
            for (int j = 0; j < BFR; ++j)
                bfr[j] = *(const bf16x8*)&Bs[(wn + j * 16 + l16) * 64 + cs];
#pragma unroll
            for (int i = 0; i < 4; ++i)
#pragma unroll
                for (int j = 0; j < BFR; ++j) acc[i][j] = mfma16(af[i], bfr[j], acc[i][j]);
        }
    }

#pragma unroll
    for (int i = 0; i < 4; ++i) {
        const int row = m0 + wm + i * 16 + q4 * 4;
#pragma unroll
        for (int j = 0; j < BFR; ++j) {
            const int col = n0 + wn + j * 16 + l16;
#pragma unroll
            for (int r = 0; r < 4; ++r) {
                const float vr = acc[i][j][r] * oscale;
                if constexpr (BF16OUT)
                    ((u16*)Cp)[(size_t)(row + r) * N + col] = f2bf(vr);
                else
                    ((float*)Cp)[(size_t)(row + r) * N + col] = vr;
            }
        }
    }
}

// z=0: Q = query@wq^T (pre-scaled by 0.125*log2e); z=1: K = key@wk^T;
// z=2: Vt = wv @ value^T -> VtAll[h*64+dv][b*2048+s]
// Activations (fp32) convert during staging; weights pre-converted bf16.
// T1: XCD-aware swizzle for z in {0,1}.
__global__ __launch_bounds__(256) void gemm_qkv(const float* __restrict__ q, const float* __restrict__ k,
                                                const float* __restrict__ v, const u16* __restrict__ wqb,
                                                const u16* __restrict__ wkb, const u16* __restrict__ wvb,
                                                u16* __restrict__ Qp, u16* __restrict__ Kp,
                                                u16* __restrict__ VtAll) {
    const int z = blockIdx.y;
    int x = blockIdx.x;
    if (z != 2) x = (x & 7) * 32 + (x >> 3);  // bijective: 256 % 8 == 0
    if (z == 0) {
        gemm_rs<true, false>(q, wqb, Qp, 1024, 1024, (x >> 3) * 128, (x & 7) * 128,
                             0.18033688011112042f);  // (1/sqrt(64)) * log2(e)
    } else if (z == 1) {
        gemm_rs<true, false>(k, wkb, Kp, 1024, 1024, (x >> 3) * 128, (x & 7) * 128, 1.0f);
    } else {
        gemm_rs<false, true>(wvb, v, VtAll, 1024, 4096, (x >> 5) * 128, (x & 31) * 128, 1.0f);
    }
}

__global__ __launch_bounds__(256) void gemm_out(const u16* __restrict__ ctx,
                                                const u16* __restrict__ wob,
                                                float* __restrict__ out) {
    // round-6 config: 64x128 tile, 512 blocks. T1 swizzle.
    const int xo = (blockIdx.x & 7) * 64 + (blockIdx.x >> 3);  // bijective: 512 % 8 == 0
    gemm_core<64, 128, false>(ctx, wob, out, 1024, 1024, (xo >> 3) * 64, (xo & 7) * 128, 1.0f);
}

// ---------------- Flash attention: 8 waves x 16 q-rows (round-3 winner, verbatim) ----
// 512 threads/block, wave owns 16 q-rows. 2 blocks/CU x 8 waves = 4 waves/SIMD.
// Per-tile: stage(buf from regs) -> prefetch(next into regs) -> barrier_nodrain
// (lgkm only; prefetch stays in flight, T4/T14) -> QK, exp, PV.
// T1: 1D grid + swizzle so each XCD owns 4 whole (h,b) groups. Measured: 56.1 us.
__global__ __launch_bounds__(512, 4) void flash_attn(const u16* __restrict__ Qp,
                                                     const u16* __restrict__ Kp,
                                                     const u16* __restrict__ VtAll,
                                                     u16* __restrict__ Ctx) {
    constexpr int D = 1024, SS = 2048, LD = 72;
    __shared__ __align__(16) u16 Ks[2][64 * LD];   // [buf][s_row][dk]
    __shared__ __align__(16) u16 Vts[2][64 * LD];  // [buf][dv][s], 8B sub-chunk swizzled

    const int tid = threadIdx.x;
    const int lane = tid & 63, wave = tid >> 6;  // 8 waves
    const int l16 = lane & 15, q4 = lane >> 4;

    const int nb = blockIdx.x;                    // 512 blocks, 1D
    const int orig = (nb & 7) * 64 + (nb >> 3);   // bijective: 512 % 8 == 0
    const int h = (orig >> 4) & 15, b = orig >> 8;
    const int q0 = (orig & 15) * 128 + wave * 16;

    bf16x8 qf[2];
    {
        const u16* Qb = Qp + (size_t)(b * SS + q0 + l16) * D + h * 64;
        qf[0] = *(const bf16x8*)(Qb + q4 * 8);
        qf[1] = *(const bf16x8*)(Qb + 32 + q4 * 8);
    }

    const f32x4 fz = {0.f, 0.f, 0.f, 0.f};
    f32x4 ot[4], lacc = fz;
#pragma unroll
    for (int dt = 0; dt < 4; ++dt) ot[dt] = fz;

    s16x4 onesA;
    onesA[0] = onesA[1] = onesA[2] = onesA[3] = (short)0x3F80;  // bf16 1.0

    // staging: 512 threads x one uint4 each covers a full 64x64 bf16 tile
    const int sr = tid >> 3;           // 0..63
    const int scol = (tid & 7) * 8;    // 8-elem (16B) chunk
    const int vswap = (sr >> 3) & 1;   // == (dv>>3)&1 for the staged row
    const int swV = (l16 >> 3) & 1;    // read-side sub-chunk swizzle key
    const u16* Kg = Kp + (size_t)(b * SS + sr) * D + h * 64 + scol;
    const u16* Vg = VtAll + (size_t)(h * 64 + sr) * 4096 + b * SS + scol;

    uint4 kv, vv;
    auto prefetch = [&](int kt) {
        kv = *(const uint4*)(Kg + (size_t)kt * D);
        vv = *(const uint4*)(Vg + kt);
    };
    auto stage = [&](int buf) {
        uint4 w = vswap ? make_uint4(vv.z, vv.w, vv.x, vv.y) : vv;  // 8B-half swap
        *(uint4*)&Ks[buf][sr * LD + scol] = kv;
        *(uint4*)&Vts[buf][sr * LD + scol] = w;
    };

    prefetch(0);
    for (int kt = 0; kt < SS; kt += 64) {
        const int buf = (kt >> 6) & 1;
        stage(buf);
        const int nk = (kt + 64 < SS) ? kt + 64 : 0;  // wrap: harmless dead load
        prefetch(nk);
        barrier_nodrain();

        // S^T = K·Q^T (exp2 domain; Q pre-scaled by 0.125*log2e)
        f32x4 st[4];
        __builtin_amdgcn_s_setprio(1);
#pragma unroll
        for (int nt = 0; nt < 4; ++nt) {
            const bf16x8 ka = *(const bf16x8*)&Ks[buf][(nt * 16 + l16) * LD + q4 * 8];
            const bf16x8 kb2 = *(const bf16x8*)&Ks[buf][(nt * 16 + l16) * LD + 32 + q4 * 8];
            f32x4 s = mfma16(ka, qf[0], fz);
            st[nt] = mfma16(kb2, qf[1], s);
        }
        __builtin_amdgcn_s_setprio(0);

        // P^T = exp2(S^T), in-register (K=16 B-frag layout)
        s16x4 p[4];
#pragma unroll
        for (int nt = 0; nt < 4; ++nt) {
#pragma unroll
            for (int r = 0; r < 4; ++r)
                p[nt][r] = (short)f2bf(__builtin_amdgcn_exp2f(st[nt][r]));
        }

        // O^T += V^T·P^T ; l via ones-MFMA (every reg = l[q=l16])
        __builtin_amdgcn_s_setprio(1);
#pragma unroll
        for (int nt = 0; nt < 4; ++nt) {
#pragma unroll
            for (int dt = 0; dt < 4; ++dt) {
                const s16x4 va =
                    *(const s16x4*)&Vts[buf][(dt * 16 + l16) * LD + ((nt * 4 + q4) ^ swV) * 4];
                ot[dt] = mfma16k16(va, p[nt], ot[dt]);
            }
            lacc = mfma16k16(onesA, p[nt], lacc);
        }
        __builtin_amdgcn_s_setprio(0);
    }

    // normalize + direct bf16 ctx write (lacc broadcast: all regs hold l[q=l16])
    {
        const float inv = 1.f / lacc[0];
        u16* Cb = Ctx + (size_t)(b * SS + q0 + l16) * D + h * 64 + q4 * 4;
#pragma unroll
        for (int dt = 0; dt < 4; ++dt) {
            s16x4 w;
#pragma unroll
            for (int r = 0; r < 4; ++r) w[r] = (short)f2bf(ot[dt][r] * inv);
            *(s16x4*)(Cb + dt * 16) = w;  // O[q][dv], dv = dt*16 + q4*4 + r
        }
    }
}

extern "C" void kernel_launch(void* const* d_in, const int* in_sizes, int n_in,
                              void* d_out, int out_size, void* d_ws, size_t ws_size,
                              hipStream_t stream) {
    const float* query = (const float*)d_in[0];
    const float* key   = (const float*)d_in[1];
    const float* value = (const float*)d_in[2];
    const float* w_q   = (const float*)d_in[3];
    const float* w_k   = (const float*)d_in[4];
    const float* w_v   = (const float*)d_in[5];
    const float* w_o   = (const float*)d_in[6];
    float* out = (float*)d_out;

    const size_t MEG = 1024 * 1024;
    if (ws_size < 40 * MEG) return;  // layout needs 40 MiB
    u16* ws = (u16*)d_ws;
    u16* wqb   = ws;
    u16* wkb   = ws + 1 * MEG;
    u16* wvb   = ws + 2 * MEG;
    u16* wob   = ws + 3 * MEG;   // live until gemm_out
    u16* Qp    = ws + 4 * MEG;
    u16* Kp    = ws + 8 * MEG;
    u16* VtAll = ws + 12 * MEG;
    u16* ctx   = ws + 16 * MEG;  // ends at 20 MEG u16 = 40 MiB

    cvt_w<<<dim3(1024, 4), 256, 0, stream>>>(w_q, w_k, w_v, w_o, wqb, wkb, wvb, wob);
    gemm_qkv<<<dim3(256, 3), 256, 0, stream>>>(query, key, value, wqb, wkb, wvb, Qp, Kp, VtAll);
    flash_attn<<<dim3(512), 512, 0, stream>>>(Qp, Kp, VtAll, ctx);
    gemm_out<<<dim3(512), 256, 0, stream>>>(ctx, wob, out);
}

// Round 9
// 215.142 us; speedup vs baseline: 1.0289x; 1.0289x over previous
//
#include <hip/hip_runtime.h>

typedef unsigned short u16;
typedef unsigned int u32;
typedef __bf16 bf16x8 __attribute__((ext_vector_type(8)));
typedef float f32x4 __attribute__((ext_vector_type(4)));
typedef short s16x4 __attribute__((ext_vector_type(4)));

#define AS1 __attribute__((address_space(1)))
#define AS3 __attribute__((address_space(3)))

__device__ __forceinline__ f32x4 mfma16(bf16x8 a, bf16x8 b, f32x4 c) {
    return __builtin_amdgcn_mfma_f32_16x16x32_bf16(a, b, c, 0, 0, 0);
}
// K=16 shape: B-operand layout == C/D layout (transpose-free PV)
__device__ __forceinline__ f32x4 mfma16k16(s16x4 a, s16x4 b, f32x4 c) {
    return __builtin_amdgcn_mfma_f32_16x16x16bf16_1k(a, b, c, 0, 0, 0);
}

__device__ __forceinline__ u16 f2bf(float f) {
    return __builtin_bit_cast(u16, (__bf16)f);
}

__device__ __forceinline__ void gld16(const u16* g, u16* l) {
    __builtin_amdgcn_global_load_lds((AS1 void*)g, (AS3 void*)l, 16, 0, 0);
}

// 8x fp32 -> 8x bf16 packed (compiler emits v_cvt_pk_bf16_f32 pairs)
__device__ __forceinline__ uint4 pack8(float4 a, float4 b) {
    return make_uint4((u32)f2bf(a.x) | ((u32)f2bf(a.y) << 16),
                      (u32)f2bf(a.z) | ((u32)f2bf(a.w) << 16),
                      (u32)f2bf(b.x) | ((u32)f2bf(b.y) << 16),
                      (u32)f2bf(b.z) | ((u32)f2bf(b.w) << 16));
}

// Raw barrier: drain LDS ops only; global prefetch loads stay in flight (T4).
__device__ __forceinline__ void barrier_nodrain() {
    asm volatile("s_waitcnt lgkmcnt(0)" ::: "memory");
    __builtin_amdgcn_s_barrier();
    asm volatile("" ::: "memory");
}

// ---------------- weights-only fp32 -> bf16 (activations convert in-GEMM) ----------
__global__ __launch_bounds__(256) void cvt_w(const float* __restrict__ wq, const float* __restrict__ wk,
                                             const float* __restrict__ wv, const float* __restrict__ wo,
                                             u16* __restrict__ wqo, u16* __restrict__ wko,
                                             u16* __restrict__ wvo, u16* __restrict__ woo) {
    const int y = blockIdx.y;
    const float* x; u16* o;
    switch (y) {
        case 0: x = wq; o = wqo; break;
        case 1: x = wk; o = wko; break;
        case 2: x = wv; o = wvo; break;
        default: x = wo; o = woo; break;
    }
    const int i = (blockIdx.x * 256 + threadIdx.x) * 4;  // grid 1024 covers 1<<20 exactly
    float4 vv = *(const float4*)(x + i);
    u32 lo = (u32)f2bf(vv.x) | ((u32)f2bf(vv.y) << 16);
    u32 hi = (u32)f2bf(vv.z) | ((u32)f2bf(vv.w) << 16);
    *(uint2*)(o + i) = make_uint2(lo, hi);
}

// ---------------- reg-staged GEMM (flash staging pattern): C = A @ Bt^T ----------------
// 128x128 tile, BK=64, 256 thr. fp32 operands convert during staging (pack8).
// Schedule per K-step (== flash_attn's): stage(buf from regs) -> prefetch(next
// K-step into regs) -> barrier_nodrain (lgkmcnt only; global loads stay in
// flight across the barrier, T4) -> MFMA.
// LDS is passed IN from the kernel (round-8 bug: per-instantiation __shared__
// arrays were SUMMED by the compiler -> 144 KB -> 1 block/CU, occupancy 9.8%.
// Sharing one kernel-level allocation gives 72 KB -> 2 blocks/CU.)
// Buffer safety: stage(t) writes buf; last read of buf was compute(t-2), and every
// wave passed barrier(t-1) only after finishing compute(t-2). LDS stride 72 elems.
template <bool AF32, bool BF32>
__device__ __forceinline__ void gemm_rs(u16* __restrict__ AsB, u16* __restrict__ BsB,
                                        const void* __restrict__ Apv, const void* __restrict__ Btv,
                                        u16* __restrict__ Cp, int K, int N, int m0, int n0,
                                        float oscale) {
    constexpr int LDT = 72;
    constexpr int BUFE = 128 * LDT;  // elems per buffer
    const int tid = threadIdx.x;
    const int lane = tid & 63, wave = tid >> 6;
    const int l16 = lane & 15, q4 = lane >> 4;
    const int wm = (wave >> 1) * 64, wn = (wave & 1) * 64;

    const f32x4 fz = {0.f, 0.f, 0.f, 0.f};
    f32x4 acc[4][4];
#pragma unroll
    for (int i = 0; i < 4; ++i)
#pragma unroll
        for (int j = 0; j < 4; ++j) acc[i][j] = fz;

    // staging: thread (sr, pos) covers rows sr+{0,32,64,96}, 16B chunk pos of each
    const int sr = tid >> 3, pos = (tid & 7) * 8;  // pos in elems
    const float* Af = (const float*)Apv + (size_t)(m0 + sr) * K + pos;
    const u16*   Ab = (const u16*)Apv + (size_t)(m0 + sr) * K + pos;
    const float* Bf = (const float*)Btv + (size_t)(n0 + sr) * K + pos;
    const u16*   Bb = (const u16*)Btv + (size_t)(n0 + sr) * K + pos;

    float4 pa[4][2], pb[4][2];
    uint4 qa[4], qb[4];
    auto prefetch = [&](int k0) {
#pragma unroll
        for (int p = 0; p < 4; ++p) {
            const size_t ro = (size_t)(p * 32) * K + k0;
            if constexpr (AF32) {
                pa[p][0] = *(const float4*)(Af + ro);
                pa[p][1] = *(const float4*)(Af + ro + 4);
            } else {
                qa[p] = *(const uint4*)(Ab + ro);
            }
            if constexpr (BF32) {
                pb[p][0] = *(const float4*)(Bf + ro);
                pb[p][1] = *(const float4*)(Bf + ro + 4);
            } else {
                qb[p] = *(const uint4*)(Bb + ro);
            }
        }
    };
    auto stage = [&](int buf) {
        u16* As = AsB + buf * BUFE;
        u16* Bs = BsB + buf * BUFE;
#pragma unroll
        for (int p = 0; p < 4; ++p) {
            uint4 wa, wb;
            if constexpr (AF32) wa = pack8(pa[p][0], pa[p][1]); else wa = qa[p];
            if constexpr (BF32) wb = pack8(pb[p][0], pb[p][1]); else wb = qb[p];
            *(uint4*)&As[(sr + p * 32) * LDT + pos] = wa;
            *(uint4*)&Bs[(sr + p * 32) * LDT + pos] = wb;
        }
    };

    prefetch(0);
    for (int k0 = 0; k0 < K; k0 += 64) {
        const int buf = (k0 >> 6) & 1;
        stage(buf);
        prefetch(k0 + 64 < K ? k0 + 64 : 0);  // wrap: harmless dead load
        barrier_nodrain();
        const u16* As = AsB + buf * BUFE;
        const u16* Bs = BsB + buf * BUFE;
#pragma unroll
        for (int h = 0; h < 2; ++h) {  // two K=32 halves of the 64-col tile
            bf16x8 af[4], bfr[4];
#pragma unroll
            for (int i = 0; i < 4; ++i)
                af[i] = *(const bf16x8*)&As[(wm + i * 16 + l16) * LDT + (h * 4 + q4) * 8];
#pragma unroll
            for (int j = 0; j < 4; ++j)
                bfr[j] = *(const bf16x8*)&Bs[(wn + j * 16 + l16) * LDT + (h * 4 + q4) * 8];
#pragma unroll
            for (int i = 0; i < 4; ++i)
#pragma unroll
                for (int j = 0; j < 4; ++j) acc[i][j] = mfma16(af[i], bfr[j], acc[i][j]);
        }
    }

#pragma unroll
    for (int i = 0; i < 4; ++i) {
        const int row = m0 + wm + i * 16 + q4 * 4;
#pragma unroll
        for (int j = 0; j < 4; ++j) {
            const int col = n0 + wn + j * 16 + l16;
#pragma unroll
            for (int r = 0; r < 4; ++r)
                Cp[(size_t)(row + r) * N + col] = f2bf(acc[i][j][r] * oscale);
        }
    }
}

// ---------------- gld16 GEMM (round-6 config, for bf16-only gemm_out) ----------------
template <int BM, int BN, bool BF16OUT>
__device__ __forceinline__ void gemm_core(const u16* __restrict__ A, const u16* __restrict__ Bt,
                                          void* __restrict__ Cp, int K, int N, int m0, int n0,
                                          float oscale) {
    constexpr int WROWS = BM / 64;
    constexpr int WCOLS = 4 / WROWS;
    constexpr int BFR = BN / WCOLS / 16;
    constexpr int RPWA = BM / 4;
    constexpr int RPWB = BN / 4;
    constexpr int PA = RPWA / 8, PB = RPWB / 8;
    __shared__ __align__(16) u16 As[BM * 64];
    __shared__ __align__(16) u16 Bs[BN * 64];
    const int tid = threadIdx.x;
    const int lane = tid & 63, wave = tid >> 6;
    const int l16 = lane & 15, q4 = lane >> 4;
    const int wm = (wave / WCOLS) * 64, wn = (wave % WCOLS) * (BFR * 16);

    const f32x4 fz = {0.f, 0.f, 0.f, 0.f};
    f32x4 acc[4][BFR];
#pragma unroll
    for (int i = 0; i < 4; ++i)
#pragma unroll
        for (int j = 0; j < BFR; ++j) acc[i][j] = fz;

    const int srow = lane >> 3;
    const int clog = (lane & 7) ^ srow;  // source pre-swizzle (gld16 dest is linear)
    const u16* Ag = A + (size_t)(m0 + wave * RPWA + srow) * K + clog * 8;
    const u16* Bg = Bt + (size_t)(n0 + wave * RPWB + srow) * K + clog * 8;
    const int rk = l16 & 7;

    for (int k0 = 0; k0 < K; k0 += 64) {
        __syncthreads();
#pragma unroll
        for (int p = 0; p < PA; ++p)
            gld16(Ag + (size_t)(p * 8) * K + k0, As + (wave * RPWA + p * 8) * 64);
#pragma unroll
        for (int p = 0; p < PB; ++p)
            gld16(Bg + (size_t)(p * 8) * K + k0, Bs + (wave * RPWB + p * 8) * 64);
        __syncthreads();
#pragma unroll
        for (int h = 0; h < 2; ++h) {
            const int cs = ((h * 4 + q4) ^ rk) * 8;
            bf16x8 af[4], bfr[BFR];
#pragma unroll
            for (int i = 0; i < 4; ++i)
                af[i] = *(const bf16x8*)&As[(wm + i * 16 + l16) * 64 + cs];
#pragma unroll
            for (int j = 0; j < BFR; ++j)
                bfr[j] = *(const bf16x8*)&Bs[(wn + j * 16 + l16) * 64 + cs];
#pragma unroll
            for (int i = 0; i < 4; ++i)
#pragma unroll
                for (int j = 0; j < BFR; ++j) acc[i][j] = mfma16(af[i], bfr[j], acc[i][j]);
        }
    }

#pragma unroll
    for (int i = 0; i < 4; ++i) {
        const int row = m0 + wm + i * 16 + q4 * 4;
#pragma unroll
        for (int j = 0; j < BFR; ++j) {
            const int col = n0 + wn + j * 16 + l16;
#pragma unroll
            for (int r = 0; r < 4; ++r) {
                const float vr = acc[i][j][r] * oscale;
                if constexpr (BF16OUT)
                    ((u16*)Cp)[(size_t)(row + r) * N + col] = f2bf(vr);
                else
                    ((float*)Cp)[(size_t)(row + r) * N + col] = vr;
            }
        }
    }
}

// z=0: Q = query@wq^T (pre-scaled by 0.125*log2e); z=1: K = key@wk^T;
// z=2: Vt = wv @ value^T -> VtAll[h*64+dv][b*2048+s]
// Activations (fp32) convert during staging; weights pre-converted bf16.
// LDS declared HERE and shared by both gemm_rs instantiations (round-8 fix).
// T1: XCD-aware swizzle for z in {0,1}.
__global__ __launch_bounds__(256) void gemm_qkv(const float* __restrict__ q, const float* __restrict__ k,
                                                const float* __restrict__ v, const u16* __restrict__ wqb,
                                                const u16* __restrict__ wkb, const u16* __restrict__ wvb,
                                                u16* __restrict__ Qp, u16* __restrict__ Kp,
                                                u16* __restrict__ VtAll) {
    __shared__ __align__(16) u16 AsB[2 * 128 * 72];
    __shared__ __align__(16) u16 BsB[2 * 128 * 72];
    const int z = blockIdx.y;
    int x = blockIdx.x;
    if (z != 2) x = (x & 7) * 32 + (x >> 3);  // bijective: 256 % 8 == 0
    if (z == 0) {
        gemm_rs<true, false>(AsB, BsB, q, wqb, Qp, 1024, 1024, (x >> 3) * 128, (x & 7) * 128,
                             0.18033688011112042f);  // (1/sqrt(64)) * log2(e)
    } else if (z == 1) {
        gemm_rs<true, false>(AsB, BsB, k, wkb, Kp, 1024, 1024, (x >> 3) * 128, (x & 7) * 128, 1.0f);
    } else {
        gemm_rs<false, true>(AsB, BsB, wvb, v, VtAll, 1024, 4096, (x >> 5) * 128, (x & 31) * 128, 1.0f);
    }
}

__global__ __launch_bounds__(256) void gemm_out(const u16* __restrict__ ctx,
                                                const u16* __restrict__ wob,
                                                float* __restrict__ out) {
    // round-6 config: 64x128 tile, 512 blocks. T1 swizzle.
    const int xo = (blockIdx.x & 7) * 64 + (blockIdx.x >> 3);  // bijective: 512 % 8 == 0
    gemm_core<64, 128, false>(ctx, wob, out, 1024, 1024, (xo >> 3) * 64, (xo & 7) * 128, 1.0f);
}

// ---------------- Flash attention: 8 waves x 16 q-rows (round-3 winner, verbatim) ----
// 512 threads/block, wave owns 16 q-rows. 2 blocks/CU x 8 waves = 4 waves/SIMD.
// Per-tile: stage(buf from regs) -> prefetch(next into regs) -> barrier_nodrain
// (lgkm only; prefetch stays in flight, T4/T14) -> QK, exp, PV.
// T1: 1D grid + swizzle so each XCD owns 4 whole (h,b) groups. Measured: 56.1 us.
__global__ __launch_bounds__(512, 4) void flash_attn(const u16* __restrict__ Qp,
                                                     const u16* __restrict__ Kp,
                                                     const u16* __restrict__ VtAll,
                                                     u16* __restrict__ Ctx) {
    constexpr int D = 1024, SS = 2048, LD = 72;
    __shared__ __align__(16) u16 Ks[2][64 * LD];   // [buf][s_row][dk]
    __shared__ __align__(16) u16 Vts[2][64 * LD];  // [buf][dv][s], 8B sub-chunk swizzled

    const int tid = threadIdx.x;
    const int lane = tid & 63, wave = tid >> 6;  // 8 waves
    const int l16 = lane & 15, q4 = lane >> 4;

    const int nb = blockIdx.x;                    // 512 blocks, 1D
    const int orig = (nb & 7) * 64 + (nb >> 3);   // bijective: 512 % 8 == 0
    const int h = (orig >> 4) & 15, b = orig >> 8;
    const int q0 = (orig & 15) * 128 + wave * 16;

    bf16x8 qf[2];
    {
        const u16* Qb = Qp + (size_t)(b * SS + q0 + l16) * D + h * 64;
        qf[0] = *(const bf16x8*)(Qb + q4 * 8);
        qf[1] = *(const bf16x8*)(Qb + 32 + q4 * 8);
    }

    const f32x4 fz = {0.f, 0.f, 0.f, 0.f};
    f32x4 ot[4], lacc = fz;
#pragma unroll
    for (int dt = 0; dt < 4; ++dt) ot[dt] = fz;

    s16x4 onesA;
    onesA[0] = onesA[1] = onesA[2] = onesA[3] = (short)0x3F80;  // bf16 1.0

    // staging: 512 threads x one uint4 each covers a full 64x64 bf16 tile
    const int sr = tid >> 3;           // 0..63
    const int scol = (tid & 7) * 8;    // 8-elem (16B) chunk
    const int vswap = (sr >> 3) & 1;   // == (dv>>3)&1 for the staged row
    const int swV = (l16 >> 3) & 1;    // read-side sub-chunk swizzle key
    const u16* Kg = Kp + (size_t)(b * SS + sr) * D + h * 64 + scol;
    const u16* Vg = VtAll + (size_t)(h * 64 + sr) * 4096 + b * SS + scol;

    uint4 kv, vv;
    auto prefetch = [&](int kt) {
        kv = *(const uint4*)(Kg + (size_t)kt * D);
        vv = *(const uint4*)(Vg + kt);
    };
    auto stage = [&](int buf) {
        uint4 w = vswap ? make_uint4(vv.z, vv.w, vv.x, vv.y) : vv;  // 8B-half swap
        *(uint4*)&Ks[buf][sr * LD + scol] = kv;
        *(uint4*)&Vts[buf][sr * LD + scol] = w;
    };

    prefetch(0);
    for (int kt = 0; kt < SS; kt += 64) {
        const int buf = (kt >> 6) & 1;
        stage(buf);
        const int nk = (kt + 64 < SS) ? kt + 64 : 0;  // wrap: harmless dead load
        prefetch(nk);
        barrier_nodrain();

        // S^T = K·Q^T (exp2 domain; Q pre-scaled by 0.125*log2e)
        f32x4 st[4];
        __builtin_amdgcn_s_setprio(1);
#pragma unroll
        for (int nt = 0; nt < 4; ++nt) {
            const bf16x8 ka = *(const bf16x8*)&Ks[buf][(nt * 16 + l16) * LD + q4 * 8];
            const bf16x8 kb2 = *(const bf16x8*)&Ks[buf][(nt * 16 + l16) * LD + 32 + q4 * 8];
            f32x4 s = mfma16(ka, qf[0], fz);
            st[nt] = mfma16(kb2, qf[1], s);
        }
        __builtin_amdgcn_s_setprio(0);

        // P^T = exp2(S^T), in-register (K=16 B-frag layout)
        s16x4 p[4];
#pragma unroll
        for (int nt = 0; nt < 4; ++nt) {
#pragma unroll
            for (int r = 0; r < 4; ++r)
                p[nt][r] = (short)f2bf(__builtin_amdgcn_exp2f(st[nt][r]));
        }

        // O^T += V^T·P^T ; l via ones-MFMA (every reg = l[q=l16])
        __builtin_amdgcn_s_setprio(1);
#pragma unroll
        for (int nt = 0; nt < 4; ++nt) {
#pragma unroll
            for (int dt = 0; dt < 4; ++dt) {
                const s16x4 va =
                    *(const s16x4*)&Vts[buf][(dt * 16 + l16) * LD + ((nt * 4 + q4) ^ swV) * 4];
                ot[dt] = mfma16k16(va, p[nt], ot[dt]);
            }
            lacc = mfma16k16(onesA, p[nt], lacc);
        }
        __builtin_amdgcn_s_setprio(0);
    }

    // normalize + direct bf16 ctx write (lacc broadcast: all regs hold l[q=l16])
    {
        const float inv = 1.f / lacc[0];
        u16* Cb = Ctx + (size_t)(b * SS + q0 + l16) * D + h * 64 + q4 * 4;
#pragma unroll
        for (int dt = 0; dt < 4; ++dt) {
            s16x4 w;
#pragma unroll
            for (int r = 0; r < 4; ++r) w[r] = (short)f2bf(ot[dt][r] * inv);
            *(s16x4*)(Cb + dt * 16) = w;  // O[q][dv], dv = dt*16 + q4*4 + r
        }
    }
}

extern "C" void kernel_launch(void* const* d_in, const int* in_sizes, int n_in,
                              void* d_out, int out_size, void* d_ws, size_t ws_size,
                              hipStream_t stream) {
    const float* query = (const float*)d_in[0];
    const float* key   = (const float*)d_in[1];
    const float* value = (const float*)d_in[2];
    const float* w_q   = (const float*)d_in[3];
    const float* w_k   = (const float*)d_in[4];
    const float* w_v   = (const float*)d_in[5];
    const float* w_o   = (const float*)d_in[6];
    float* out = (float*)d_out;

    const size_t MEG = 1024 * 1024;
    if (ws_size < 40 * MEG) return;  // layout needs 40 MiB
    u16* ws = (u16*)d_ws;
    u16* wqb   = ws;
    u16* wkb   = ws + 1 * MEG;
    u16* wvb   = ws + 2 * MEG;
    u16* wob   = ws + 3 * MEG;   // live until gemm_out
    u16* Qp    = ws + 4 * MEG;
    u16* Kp    = ws + 8 * MEG;
    u16* VtAll = ws + 12 * MEG;
    u16* ctx   = ws + 16 * MEG;  // ends at 20 MEG u16 = 40 MiB

    cvt_w<<<dim3(1024, 4), 256, 0, stream>>>(w_q, w_k, w_v, w_o, wqb, wkb, wvb, wob);
    gemm_qkv<<<dim3(256, 3), 256, 0, stream>>>(query, key, value, wqb, wkb, wvb, Qp, Kp, VtAll);
    flash_attn<<<dim3(512), 512, 0, stream>>>(Qp, Kp, VtAll, ctx);
    gemm_out<<<dim3(512), 256, 0, stream>>>(ctx, wob, out);
}